// Round 16
// baseline (872.288 us; speedup 1.0000x reference)
//
#include <hip/hip_runtime.h>
#include <math.h>

// Problem constants
#define NN 50000      // nodes
#define NE 800000     // edges
#define HD 512        // hidden
#define GN_EPS 1e-5f
#define NBCHUNK 196   // ceil(NN/256) for scan
#define GRIDM 391     // ceil(NN/128) GEMM row panels (BM=128)
#define STATS_NB 512  // combine1 stats partial blocks
#define RCH 64        // reduction chunks

typedef __attribute__((ext_vector_type(4))) float f4;
typedef __attribute__((ext_vector_type(4))) float f32x4;
typedef __attribute__((ext_vector_type(8))) short short8;
typedef unsigned short u16;
typedef __attribute__((ext_vector_type(4))) unsigned short us4;
typedef __attribute__((ext_vector_type(8))) unsigned short us8;

typedef struct { int s; float w; } edge_t;   // packed (src, norm) 8B

static __device__ __forceinline__ float elu1(float v){ return v > 0.f ? v : expm1f(v); }

static __device__ __forceinline__ float bf2f(u16 u){
  union { unsigned int i; float f; } v; v.i = ((unsigned int)u) << 16; return v.f;
}
static __device__ __forceinline__ u16 f2bf(float f){
  union { float f; unsigned int i; } v; v.f = f;
  unsigned int b = v.i;
  b += 0x7FFFu + ((b >> 16) & 1u);   // round-to-nearest-even
  return (u16)(b >> 16);
}

// A/B tile LDS address ([row][128B]): XOR 16B-slot index with (row&7); both-side swizzle.
static __device__ __forceinline__ int lds_addr(int row, int chunkByte){
  return row*128 + (chunkByte ^ ((row & 7) << 4));
}
// C tile LDS address in u16 units ([row][128 u16]): XOR 8-u16 chunk index with (row&7).
static __device__ __forceinline__ int ct_addr(int row, int col){
  return row*128 + (col ^ ((row & 7) << 3));
}

// ---------------- CSR build ----------------
__global__ void k_deg(const int* __restrict__ dst, const float* __restrict__ w,
                      float* __restrict__ deg, int* __restrict__ cnt) {
  int e = blockIdx.x*256 + threadIdx.x;
  if (e < NE) {
    int d = dst[e];
    atomicAdd(&deg[d], w[e]);
    atomicAdd(&cnt[d], 1);
  }
}

// hierarchical scan: chunk-local inclusive -> chunk totals; also deg -> rsqrt in place
__global__ void __launch_bounds__(256) k_scanA(const int* __restrict__ cnt,
                                               int* __restrict__ row_ptr,
                                               int* __restrict__ btot,
                                               float* __restrict__ deg) {
  __shared__ int sh[256];
  int t = threadIdx.x, b = blockIdx.x;
  int i = b*256 + t;
  if (i < NN) { float d = deg[i]; deg[i] = d > 0.f ? rsqrtf(d) : 0.f; }
  int v = (i < NN) ? cnt[i] : 0;
  sh[t] = v; __syncthreads();
  #pragma unroll
  for (int off = 1; off < 256; off <<= 1) {
    int x = (t >= off) ? sh[t-off] : 0;
    __syncthreads();
    sh[t] += x;
    __syncthreads();
  }
  if (i < NN) row_ptr[i+1] = sh[t];
  if (t == 255) btot[b] = sh[255];
}

__global__ void __launch_bounds__(256) k_scanB(const int* __restrict__ btot,
                                               int* __restrict__ boff) {
  __shared__ int sh[256];
  int t = threadIdx.x;
  int v = (t < NBCHUNK) ? btot[t] : 0;
  sh[t] = v; __syncthreads();
  #pragma unroll
  for (int off = 1; off < 256; off <<= 1) {
    int x = (t >= off) ? sh[t-off] : 0;
    __syncthreads();
    sh[t] += x;
    __syncthreads();
  }
  if (t < NBCHUNK) boff[t] = sh[t] - v;   // exclusive
}

__global__ void __launch_bounds__(256) k_scanC(int* __restrict__ row_ptr,
                                               const int* __restrict__ boff) {
  int t = threadIdx.x, b = blockIdx.x;
  int i = b*256 + t;
  if (i < NN) row_ptr[i+1] += boff[b];
  if (i == 0) row_ptr[0] = 0;
}

__global__ void k_fill(const int* __restrict__ src, const int* __restrict__ dst,
                       const float* __restrict__ w, const float* __restrict__ dinv,
                       const int* __restrict__ row_ptr, int* __restrict__ cursor,
                       edge_t* __restrict__ edges) {
  int e = blockIdx.x*256 + threadIdx.x;
  if (e < NE) {
    int s = src[e], d = dst[e];
    int pos = atomicAdd(&cursor[d], 1);
    int idx = row_ptr[d] + pos;
    edge_t ed; ed.s = s; ed.w = dinv[s] * w[e] * dinv[d];
    edges[idx] = ed;
  }
}

// ---------------- width-4 propagation (layers 1 & 3), 4-edge pipelined ----------------
__global__ void k_prop4(const int* __restrict__ row_ptr, const edge_t* __restrict__ edges,
                        const f4* __restrict__ in1, const f4* __restrict__ in2,
                        const f4* __restrict__ base, const float* __restrict__ bias,
                        f4* __restrict__ out) {
  int n = blockIdx.x*256 + threadIdx.x;
  if (n >= NN) return;
  f4 acc = {0.f,0.f,0.f,0.f};
  int e0 = row_ptr[n], e1 = row_ptr[n+1];
  int e = e0;
  if (in2) {
    for (; e + 4 <= e1; e += 4) {
      edge_t d0 = edges[e], d1 = edges[e+1], d2 = edges[e+2], d3 = edges[e+3];
      f4 a0 = in1[d0.s] + in2[d0.s];
      f4 a1 = in1[d1.s] + in2[d1.s];
      f4 a2 = in1[d2.s] + in2[d2.s];
      f4 a3 = in1[d3.s] + in2[d3.s];
      acc += d0.w*a0 + d1.w*a1 + d2.w*a2 + d3.w*a3;
    }
    for (; e < e1; ++e) {
      edge_t ed = edges[e];
      acc += ed.w * (in1[ed.s] + in2[ed.s]);
    }
  } else {
    for (; e + 4 <= e1; e += 4) {
      edge_t d0 = edges[e], d1 = edges[e+1], d2 = edges[e+2], d3 = edges[e+3];
      f4 a0 = in1[d0.s], a1 = in1[d1.s], a2 = in1[d2.s], a3 = in1[d3.s];
      acc += d0.w*a0 + d1.w*a1 + d2.w*a2 + d3.w*a3;
    }
    for (; e < e1; ++e) {
      edge_t ed = edges[e];
      acc += ed.w * in1[ed.s];
    }
  }
  if (base) acc += base[n];
  if (bias) { acc[0]+=bias[0]; acc[1]+=bias[1]; acc[2]+=bias[2]; acc[3]+=bias[3]; }
  out[n] = acc;
}

// ---------------- width-512 propagation on bf16, 16-edge (2x8 batch) pipelined ----------------
// NRM=1: out = sc * (sum w v) + sh * (sum w)  (GraphNorm affine folded into the gather)
template<int NRM>
__global__ void __launch_bounds__(256) k_prop512_bf(
    const int* __restrict__ row_ptr, const edge_t* __restrict__ edges,
    const u16* __restrict__ in, u16* __restrict__ out,
    const float* __restrict__ sc, const float* __restrict__ sh) {
  int wv = threadIdx.x >> 6;
  int l  = threadIdx.x & 63;
  int n = blockIdx.x*4 + wv;
  if (n >= NN) return;
  int e0 = row_ptr[n], e1 = row_ptr[n+1];
  float acc[8] = {0.f,0.f,0.f,0.f,0.f,0.f,0.f,0.f};
  float wsum = 0.f;
  const u16* basep = in + l*8;
  int e = e0;
  // 16-edge software pipeline: issue batch-B's 8 gathers before consuming batch-A
  for (; e + 16 <= e1; e += 16) {
    edge_t edA[8], edB[8];
    us8 vA[8], vB[8];
    #pragma unroll
    for (int j = 0; j < 8; ++j) edA[j] = edges[e+j];
    #pragma unroll
    for (int j = 0; j < 8; ++j)
      vA[j] = *reinterpret_cast<const us8*>(basep + (size_t)edA[j].s*HD);
    #pragma unroll
    for (int j = 0; j < 8; ++j) edB[j] = edges[e+8+j];
    #pragma unroll
    for (int j = 0; j < 8; ++j)
      vB[j] = *reinterpret_cast<const us8*>(basep + (size_t)edB[j].s*HD);
    #pragma unroll
    for (int q = 0; q < 8; ++q) {
      float s = 0.f;
      #pragma unroll
      for (int j = 0; j < 8; ++j) s += edA[j].w * bf2f(vA[j][q]);
      acc[q] += s;
    }
    #pragma unroll
    for (int q = 0; q < 8; ++q) {
      float s = 0.f;
      #pragma unroll
      for (int j = 0; j < 8; ++j) s += edB[j].w * bf2f(vB[j][q]);
      acc[q] += s;
    }
    if (NRM) {
      #pragma unroll
      for (int j = 0; j < 8; ++j) wsum += edA[j].w + edB[j].w;
    }
  }
  for (; e + 8 <= e1; e += 8) {
    edge_t ed[8];
    us8 v[8];
    #pragma unroll
    for (int j = 0; j < 8; ++j) ed[j] = edges[e+j];
    #pragma unroll
    for (int j = 0; j < 8; ++j)
      v[j] = *reinterpret_cast<const us8*>(basep + (size_t)ed[j].s*HD);
    #pragma unroll
    for (int q = 0; q < 8; ++q) {
      float s = 0.f;
      #pragma unroll
      for (int j = 0; j < 8; ++j) s += ed[j].w * bf2f(v[j][q]);
      acc[q] += s;
    }
    if (NRM) {
      #pragma unroll
      for (int j = 0; j < 8; ++j) wsum += ed[j].w;
    }
  }
  for (; e < e1; ++e) {
    edge_t ed = edges[e];
    us8 v = *reinterpret_cast<const us8*>(basep + (size_t)ed.s*HD);
    #pragma unroll
    for (int q = 0; q < 8; ++q) acc[q] += ed.w * bf2f(v[q]);
    if (NRM) wsum += ed.w;
  }
  us8 o;
  if (NRM) {
    #pragma unroll
    for (int q = 0; q < 8; ++q)
      o[q] = f2bf(sc[l*8+q]*acc[q] + sh[l*8+q]*wsum);
  } else {
    #pragma unroll
    for (int q = 0; q < 8; ++q) o[q] = f2bf(acc[q]);
  }
  *reinterpret_cast<us8*>(out + (size_t)n*HD + l*8) = o;
}

// ---------------- layer-1 combine fused with stats: bf16 out + column partials ----------------
__global__ void __launch_bounds__(256) k_combine1s(
    const f4* __restrict__ x, const f4* __restrict__ h1, const f4* __restrict__ h2,
    const f4* __restrict__ h3, const float* __restrict__ W1, const float* __restrict__ b1,
    u16* __restrict__ act, float* __restrict__ pS, float* __restrict__ pQ) {
  __shared__ float sdS[HD], sdQ[HD];
  int t = threadIdx.x;
  int half = t >> 7;
  int c4 = (t & 127) * 4;
  f4 wcol[16];
  #pragma unroll
  for (int kf = 0; kf < 16; ++kf)
    wcol[kf] = *reinterpret_cast<const f4*>(W1 + (size_t)kf*HD + c4);
  f4 bv = *reinterpret_cast<const f4*>(b1 + c4);
  f4 s = {0.f,0.f,0.f,0.f}, qq = {0.f,0.f,0.f,0.f};
  for (int n = blockIdx.x*2 + half; n < NN; n += gridDim.x*2) {
    f4 hv0 = x[n], hv1 = h1[n], hv2 = h2[n], hv3 = h3[n];
    f4 acc = bv;
    #pragma unroll
    for (int f = 0; f < 4; ++f) acc += hv0[f] * wcol[f];
    #pragma unroll
    for (int f = 0; f < 4; ++f) acc += hv1[f] * wcol[4+f];
    #pragma unroll
    for (int f = 0; f < 4; ++f) acc += hv2[f] * wcol[8+f];
    #pragma unroll
    for (int f = 0; f < 4; ++f) acc += hv3[f] * wcol[12+f];
    us4 o;
    #pragma unroll
    for (int e = 0; e < 4; ++e) {
      float v = elu1(acc[e]);
      s[e] += v; qq[e] += v*v;
      o[e] = f2bf(v);
    }
    *reinterpret_cast<us4*>(act + (size_t)n*HD + c4) = o;
  }
  if (half) {
    *reinterpret_cast<f4*>(&sdS[c4]) = s;
    *reinterpret_cast<f4*>(&sdQ[c4]) = qq;
  }
  __syncthreads();
  if (!half) {
    f4 ts = *reinterpret_cast<f4*>(&sdS[c4]) + s;
    f4 tq = *reinterpret_cast<f4*>(&sdQ[c4]) + qq;
    *reinterpret_cast<f4*>(&pS[(size_t)blockIdx.x*HD + c4]) = ts;
    *reinterpret_cast<f4*>(&pQ[(size_t)blockIdx.x*HD + c4]) = tq;
  }
}

// ---------------- stage-1 column reduce: [nb][512] -> [RCH][512] ----------------
__global__ void __launch_bounds__(256) k_colsum(
    const float* __restrict__ pS, const float* __restrict__ pQ, int nb, int chunk,
    float* __restrict__ pS2, float* __restrict__ pQ2) {
  int c = blockIdx.x*256 + threadIdx.x;   // 0..511 over grid.x==2
  int y = blockIdx.y;                     // 0..RCH-1
  int i0 = y*chunk;
  int i1 = i0 + chunk; if (i1 > nb) i1 = nb;
  float a = 0.f, b = 0.f;
  for (int i = i0; i < i1; ++i) {
    a += pS[(size_t)i*HD + c];
    b += pQ[(size_t)i*HD + c];
  }
  pS2[(size_t)y*HD + c] = a;
  pQ2[(size_t)y*HD + c] = b;
}

// ---------------- stage-2: reduce RCH partials + GraphNorm affine ----------------
__global__ void __launch_bounds__(256) k_redaff(
    const float* __restrict__ pS2, const float* __restrict__ pQ2,
    const float* __restrict__ gw, const float* __restrict__ gb,
    const float* __restrict__ ga,
    float* __restrict__ sc, float* __restrict__ sh) {
  int c = blockIdx.x*256 + threadIdx.x;
  if (c >= HD) return;
  float a = 0.f, b = 0.f;
  #pragma unroll 8
  for (int i = 0; i < RCH; ++i) {
    a += pS2[(size_t)i*HD + c];
    b += pQ2[(size_t)i*HD + c];
  }
  float mu = a*(1.f/NN);
  float al = ga[c];
  float var = b*(1.f/NN) - 2.f*al*mu*mu + al*al*mu*mu;
  float inv = rsqrtf(var + GN_EPS);
  sc[c] = gw[c]*inv;
  sh[c] = gb[c] - gw[c]*inv*al*mu;
}

// ---------------- W2 -> bf16 transposed: Bt[k][out][in] = bf16(W2[k][in][out]) ----------------
__global__ void k_w2t(const float* __restrict__ W2, u16* __restrict__ Bt) {
  size_t idx = (size_t)blockIdx.x*256 + threadIdx.x;
  if (idx >= (size_t)4*HD*HD) return;
  int i = (int)(idx & 511);          // in  (fastest -> coalesced write)
  int o = (int)((idx >> 9) & 511);   // out
  int k = (int)(idx >> 18);
  Bt[idx] = f2bf(W2[((size_t)k*HD + i)*HD + o]);
}

// W0 slice with sc folded: Bt0[o][i] = bf16(sc[i]*W2[0][i][o])
__global__ void k_w2t0(const float* __restrict__ W2, const float* __restrict__ sc,
                       u16* __restrict__ Bt0) {
  size_t idx = (size_t)blockIdx.x*256 + threadIdx.x;
  if (idx >= (size_t)HD*HD) return;
  int i = (int)(idx & 511);
  int o = (int)(idx >> 9);
  Bt0[idx] = f2bf(sc[i] * W2[(size_t)i*HD + o]);
}

// cvec stage 1: cpart[y][o] = sum_{i in chunk y} sh[i]*W2[0][i][o]  (8 rows/chunk)
__global__ void __launch_bounds__(256) k_cvecp(const float* __restrict__ W2,
                                               const float* __restrict__ sh,
                                               float* __restrict__ cpart) {
  int o = blockIdx.x*256 + threadIdx.x;   // grid.x==2
  int y = blockIdx.y;                     // 0..63
  float a = 0.f;
  #pragma unroll
  for (int i = y*8; i < y*8 + 8; ++i) a += sh[i]*W2[(size_t)i*HD + o];
  cpart[(size_t)y*HD + o] = a;
}

// cvec stage 2
__global__ void __launch_bounds__(256) k_cvecr(const float* __restrict__ cpart,
                                               float* __restrict__ cvec) {
  int o = blockIdx.x*256 + threadIdx.x;
  if (o >= HD) return;
  float a = 0.f;
  #pragma unroll 8
  for (int y = 0; y < 64; ++y) a += cpart[(size_t)y*HD + o];
  cvec[o] = a;
}

// ---------------- MFMA bf16 dual-source GEMM (K=1024): Cbf (+)= A0@B0^T + A1@B1^T ----------------
// 2-deep A prefetch (ping-pong raP/raQ), 1-deep B. Single-pass LDS-staged coalesced C epilogue.
#define BM 128
#define BN 128
#define BKS 64
template<int FINAL>
__global__ void __launch_bounds__(256) k_gemm2(
    const u16* __restrict__ A0, const u16* __restrict__ A1,
    const u16* __restrict__ B0, const u16* __restrict__ B1,
    u16* __restrict__ Cbf, const float* __restrict__ bias,
    float* __restrict__ pS, float* __restrict__ pQ, int M) {
  __shared__ u16 smem[BM*BKS*2];   // 32 KB: As|Bs during K-loop, C tile in epilogue
  __shared__ float sdS[BN], sdQ[BN];
  u16* As = smem;
  u16* Bs = smem + BM*BKS;
  int t = threadIdx.x;

  // XCD-bijective remap (m204), col-fastest within consecutive ids
  int nwg = gridDim.x;            // GRIDM*4
  int q = nwg >> 3, r = nwg & 7;
  int xcd = blockIdx.x & 7, sub = blockIdx.x >> 3;
  int nid = (xcd < r ? xcd*(q+1) : r*(q+1) + (xcd - r)*q) + sub;
  int bmi = nid >> 2;             // row-panel index (0..GRIDM-1)
  int bni = nid & 3;              // col-panel index (0..3)
  int bm = bmi * BM, bn = bni * BN;

  int w  = t >> 6;
  int l  = t & 63;
  int wr = (w >> 1) * 64;
  int wc = (w & 1) * 64;
  int lr = l & 15;
  int lq = l >> 4;

  if (FINAL && t < BN) { sdS[t] = 0.f; sdQ[t] = 0.f; }

  // staging map: 4 slots/thread; slot s -> row = s>>3, 16B-chunk c8 = s&7
  size_t aoffs[4], boffs[4];
  int wb[4];
  #pragma unroll
  for (int p2 = 0; p2 < 4; ++p2) {
    int s = p2*256 + t;
    int row = s >> 3, c8 = s & 7;
    int ga = bm + row; if (ga >= M) ga = M - 1;
    aoffs[p2] = (size_t)ga*HD + c8*8;
    boffs[p2] = (size_t)(bn + row)*HD + c8*8;
    wb[p2] = lds_addr(row, c8*16);
  }

  f32x4 acc[4][4];
  #pragma unroll
  for (int i = 0; i < 4; ++i)
    #pragma unroll
    for (int j = 0; j < 4; ++j) acc[i][j] = (f32x4){0.f,0.f,0.f,0.f};

  us8 raP[4], raQ[4], rb[4];
  #pragma unroll
  for (int p2 = 0; p2 < 4; ++p2) {
    raP[p2] = *reinterpret_cast<const us8*>(A0 + aoffs[p2]);          // A k-tile 0
    raQ[p2] = *reinterpret_cast<const us8*>(A0 + aoffs[p2] + BKS);    // A k-tile 1
    rb[p2]  = *reinterpret_cast<const us8*>(B0 + boffs[p2]);          // B k-tile 0
  }

#define GEMM_ITER(RA, H)                                                      \
  {                                                                           \
    __syncthreads();                                                          \
    _Pragma("unroll")                                                         \
    for (int p2 = 0; p2 < 4; ++p2) {                                          \
      *reinterpret_cast<us8*>((char*)As + wb[p2]) = RA[p2];                   \
      *reinterpret_cast<us8*>((char*)Bs + wb[p2]) = rb[p2];                   \
    }                                                                         \
    if ((H) + 1 < 16) {                                                       \
      const u16* Bsrc = ((H)+1 < 8) ? B0 : B1;                                \
      int offB = (((H)+1) & 7) * BKS;                                         \
      _Pragma("unroll")                                                       \
      for (int p2 = 0; p2 < 4; ++p2)                                          \
        rb[p2] = *reinterpret_cast<const us8*>(Bsrc + boffs[p2] + offB);      \
    }                                                                         \
    if ((H) + 2 < 16) {                                                       \
      const u16* Asrc = ((H)+2 < 8) ? A0 : A1;                                \
      int offA = (((H)+2) & 7) * BKS;                                         \
      _Pragma("unroll")                                                       \
      for (int p2 = 0; p2 < 4; ++p2)                                          \
        RA[p2] = *reinterpret_cast<const us8*>(Asrc + aoffs[p2] + offA);      \
    }                                                                         \
    __syncthreads();                                                          \
    _Pragma("unroll")                                                         \
    for (int ks = 0; ks < 2; ++ks) {                                          \
      short8 af[4], bfr[4];                                                   \
      _Pragma("unroll")                                                       \
      for (int mi = 0; mi < 4; ++mi)                                          \
        af[mi] = *reinterpret_cast<const short8*>(                            \
            (char*)As + lds_addr(wr + mi*16 + lr, ks*64 + lq*16));            \
      _Pragma("unroll")                                                       \
      for (int ni = 0; ni < 4; ++ni)                                          \
        bfr[ni] = *reinterpret_cast<const short8*>(                           \
            (char*)Bs + lds_addr(wc + ni*16 + lr, ks*64 + lq*16));            \
      _Pragma("unroll")                                                       \
      for (int mi = 0; mi < 4; ++mi)                                          \
        _Pragma("unroll")                                                     \
        for (int ni = 0; ni < 4; ++ni)                                        \
          acc[mi][ni] = __builtin_amdgcn_mfma_f32_16x16x32_bf16(              \
              af[mi], bfr[ni], acc[mi][ni], 0, 0, 0);                         \
    }                                                                         \
  }

  #pragma unroll
  for (int j = 0; j < 8; ++j) {
    GEMM_ITER(raP, 2*j)
    GEMM_ITER(raQ, 2*j + 1)
  }
#undef GEMM_ITER

  // -------- epilogue: LDS-staged coalesced C path (round-9) --------
  __syncthreads();   // all ds_reads of the last tile done; smem now reusable as C tile

  int crow = t >> 1, chh = t & 1;              // cooperative row / half assignment
  if (FINAL) {
    if (bm + crow < M) {                       // coalesced load of old C into LDS
      #pragma unroll
      for (int c = 0; c < 8; ++c) {
        int col = chh*64 + c*8;
        us8 v = *reinterpret_cast<const us8*>(&Cbf[(size_t)(bm+crow)*HD + bn + col]);
        *reinterpret_cast<us8*>(&smem[ct_addr(crow, col)]) = v;
      }
    }
    __syncthreads();
  }

  float psum[4] = {0.f,0.f,0.f,0.f}, qsum[4] = {0.f,0.f,0.f,0.f};
  #pragma unroll
  for (int ni = 0; ni < 4; ++ni) {
    int coln = wc + ni*16 + lr;
    float bgn = bias ? bias[bn + coln] : 0.f;
    #pragma unroll
    for (int mi = 0; mi < 4; ++mi)
      #pragma unroll
      for (int rr = 0; rr < 4; ++rr) {
        int row = wr + mi*16 + lq*4 + rr;
        int ca = ct_addr(row, coln);
        if (!FINAL) {
          smem[ca] = f2bf(acc[mi][ni][rr] + bgn);
        } else if (bm + row < M) {
          float v = elu1(bf2f(smem[ca]) + acc[mi][ni][rr] + bgn);
          smem[ca] = f2bf(v);
          psum[ni] += v; qsum[ni] += v*v;
        }
      }
  }
  if (FINAL) {
    #pragma unroll
    for (int ni = 0; ni < 4; ++ni) {
      psum[ni] += __shfl_xor(psum[ni], 16, 64);
      psum[ni] += __shfl_xor(psum[ni], 32, 64);
      qsum[ni] += __shfl_xor(qsum[ni], 16, 64);
      qsum[ni] += __shfl_xor(qsum[ni], 32, 64);
    }
    if (lq == 0) {
      #pragma unroll
      for (int ni = 0; ni < 4; ++ni) {
        atomicAdd(&sdS[wc + ni*16 + lr], psum[ni]);   // exactly 2 contribs/slot
        atomicAdd(&sdQ[wc + ni*16 + lr], qsum[ni]);
      }
    }
  }
  __syncthreads();   // C tile complete (and sdS/sdQ final)

  if (bm + crow < M) {                          // coalesced store of C tile
    #pragma unroll
    for (int c = 0; c < 8; ++c) {
      int col = chh*64 + c*8;
      us8 v = *reinterpret_cast<const us8*>(&smem[ct_addr(crow, col)]);
      *reinterpret_cast<us8*>(&Cbf[(size_t)(bm+crow)*HD + bn + col]) = v;
    }
  }
  if (FINAL && t < BN) {
    pS[(size_t)bmi*HD + bn + t] = sdS[t];
    pQ[(size_t)bmi*HD + bn + t] = sdQ[t];
  }
}

// ---------------- layer-3 linears (bf16 act) with fused GraphNorm affine ----------------
__global__ void __launch_bounds__(256) k_lin3(
    const u16* __restrict__ act, const float* __restrict__ sc, const float* __restrict__ sh,
    const float* __restrict__ W3,
    f4* __restrict__ p0, f4* __restrict__ p1, f4* __restrict__ p2, f4* __restrict__ p3) {
  int wave = threadIdx.x / 64;
  int lane = threadIdx.x % 64;
  int n = blockIdx.x*4 + wave;
  if (n >= NN) return;
  float part[4][4] = {};
  #pragma unroll
  for (int jj = 0; jj < 8; ++jj) {
    int j = lane + jj*64;
    float v = sc[j]*bf2f(act[(size_t)n*HD + j]) + sh[j];
    #pragma unroll
    for (int k = 0; k < 4; ++k) {
      f4 wv = *reinterpret_cast<const f4*>(W3 + ((size_t)k*HD + j)*4);
      #pragma unroll
      for (int c = 0; c < 4; ++c) part[k][c] += v * wv[c];
    }
  }
  #pragma unroll
  for (int k = 0; k < 4; ++k)
    #pragma unroll
    for (int c = 0; c < 4; ++c) {
      float s = part[k][c];
      #pragma unroll
      for (int off = 32; off >= 1; off >>= 1) s += __shfl_xor(s, off, 64);
      part[k][c] = s;
    }
  if (lane == 0) {
    f4 v0 = {part[0][0],part[0][1],part[0][2],part[0][3]};
    f4 v1 = {part[1][0],part[1][1],part[1][2],part[1][3]};
    f4 v2 = {part[2][0],part[2][1],part[2][2],part[2][3]};
    f4 v3 = {part[3][0],part[3][1],part[3][2],part[3][3]};
    p0[n]=v0; p1[n]=v1; p2[n]=v2; p3[n]=v3;
  }
}

// ---------------- host launch ----------------
extern "C" void kernel_launch(void* const* d_in, const int* in_sizes, int n_in,
                              void* d_out, int out_size, void* d_ws, size_t ws_size,
                              hipStream_t stream) {
  const float* x   = (const float*)d_in[0];
  const int*   ei  = (const int*)d_in[1];
  const int*   src = ei;
  const int*   dst = ei + NE;
  const float* w   = (const float*)d_in[2];
  const float* W1  = (const float*)d_in[3];
  const float* b1  = (const float*)d_in[4];
  const float* W2  = (const float*)d_in[5];
  const float* b2  = (const float*)d_in[6];
  const float* W3  = (const float*)d_in[7];
  const float* b3  = (const float*)d_in[8];
  const float* g1w = (const float*)d_in[9];
  const float* g1b = (const float*)d_in[10];
  const float* g1a = (const float*)d_in[11];
  const float* g2w = (const float*)d_in[12];
  const float* g2b = (const float*)d_in[13];
  const float* g2a = (const float*)d_in[14];

  char* p = (char*)d_ws;
  auto alloc = [&](size_t bytes) -> void* {
    void* r = (void*)p;
    p += (bytes + 255) & ~(size_t)255;
    return r;
  };
  float* deg      = (float*)alloc(NN*4);
  int*   cnt      = (int*)  alloc(NN*4);
  int*   row_ptr  = (int*)  alloc((NN+1)*4);
  int*   cursor   = (int*)  alloc(NN*4);
  int*   btot     = (int*)  alloc(256*4);
  int*   boff     = (int*)  alloc(256*4);
  edge_t* edges   = (edge_t*)alloc((size_t)NE*8);
  f4*    h1       = (f4*)   alloc((size_t)NN*16);
  f4*    h2       = (f4*)   alloc((size_t)NN*16);
  f4*    h3       = (f4*)   alloc((size_t)NN*16);
  f4*    p0       = (f4*)   alloc((size_t)NN*16);
  f4*    p1       = (f4*)   alloc((size_t)NN*16);
  f4*    p2       = (f4*)   alloc((size_t)NN*16);
  f4*    p3       = (f4*)   alloc((size_t)NN*16);
  f4*    t1       = (f4*)   alloc((size_t)NN*16);
  f4*    t2       = (f4*)   alloc((size_t)NN*16);
  float* scb      = (float*)alloc(HD*4);
  float* shb      = (float*)alloc(HD*4);
  float* cvec     = (float*)alloc(HD*4);
  float* pS       = (float*)alloc((size_t)STATS_NB*HD*4);   // 1 MB
  float* pQ       = (float*)alloc((size_t)STATS_NB*HD*4);   // 1 MB
  float* pS2      = (float*)alloc((size_t)RCH*HD*4);        // 128 KB
  float* pQ2      = (float*)alloc((size_t)RCH*HD*4);        // 128 KB
  float* cpart    = (float*)alloc((size_t)RCH*HD*4);        // 128 KB
  u16*   W2T      = (u16*)  alloc((size_t)4*HD*HD*2);       // 2 MB
  // big buffers: 3 x 51.2 MB bf16  (~175 MB total)
  u16*   bfA      = (u16*)  alloc((size_t)NN*HD*2);
  u16*   bfB      = (u16*)  alloc((size_t)NN*HD*2);
  u16*   bfC      = (u16*)  alloc((size_t)NN*HD*2);   // C partial then act2

  const int TPB = 256;
  int gridE = (NE + TPB - 1)/TPB;
  int gridN = (NN + TPB - 1)/TPB;
  int gridP = (NN + 3)/4;

  // CSR + norm
  hipMemsetAsync(deg, 0, NN*4, stream);
  hipMemsetAsync(cnt, 0, NN*4, stream);
  k_deg<<<gridE, TPB, 0, stream>>>(dst, w, deg, cnt);
  k_scanA<<<NBCHUNK, 256, 0, stream>>>(cnt, row_ptr, btot, deg);
  k_scanB<<<1, 256, 0, stream>>>(btot, boff);
  k_scanC<<<NBCHUNK, 256, 0, stream>>>(row_ptr, boff);
  hipMemsetAsync(cursor, 0, NN*4, stream);
  k_fill<<<gridE, TPB, 0, stream>>>(src, dst, w, deg, row_ptr, cursor, edges);
  k_w2t<<<(4*HD*HD + 255)/256, 256, 0, stream>>>(W2, W2T);

  // Layer 1: hops, then fused combine+ELU+stats -> bf16 act (pre-norm) in bfA
  k_prop4<<<gridN, TPB, 0, stream>>>(row_ptr, edges, (const f4*)x, nullptr, nullptr, nullptr, h1);
  k_prop4<<<gridN, TPB, 0, stream>>>(row_ptr, edges, h1, nullptr, nullptr, nullptr, h2);
  k_prop4<<<gridN, TPB, 0, stream>>>(row_ptr, edges, h2, nullptr, nullptr, nullptr, h3);
  k_combine1s<<<STATS_NB, 256, 0, stream>>>((const f4*)x, h1, h2, h3, W1, b1, bfA, pS, pQ);
  k_colsum<<<dim3(2, RCH), 256, 0, stream>>>(pS, pQ, STATS_NB, (STATS_NB + RCH - 1)/RCH, pS2, pQ2);
  k_redaff<<<2, 256, 0, stream>>>(pS2, pQ2, g1w, g1b, g1a, scb, shb);

  // Fold GraphNorm-1 into the GEMM path: W0' = diag(sc)W0, cvec = sh^T W0
  k_w2t0<<<(HD*HD + 255)/256, 256, 0, stream>>>(W2, scb, W2T);
  k_cvecp<<<dim3(2, 64), 256, 0, stream>>>(W2, shb, cpart);
  k_cvecr<<<2, 256, 0, stream>>>(cpart, cvec);

  // Layer 2: h0=bfA (pre-norm), h1 = NRM-prop(h0) = bfB (normalized inline);
  //          GEMM1 (W0'+cvec, W1) writes Cbf; h2=prop(h1)=bfA, h3=prop(h2)=bfB;
  //          GEMM2 (W2,W3) RMW + bias+ELU+stats
  k_prop512_bf<1><<<gridP, 256, 0, stream>>>(row_ptr, edges, bfA, bfB, scb, shb);
  k_gemm2<0><<<GRIDM*4, 256, 0, stream>>>(bfA, bfB, W2T, W2T + (size_t)HD*HD,
                                          bfC, cvec, nullptr, nullptr, NN);
  k_prop512_bf<0><<<gridP, 256, 0, stream>>>(row_ptr, edges, bfB, bfA, nullptr, nullptr);
  k_prop512_bf<0><<<gridP, 256, 0, stream>>>(row_ptr, edges, bfA, bfB, nullptr, nullptr);
  k_gemm2<1><<<GRIDM*4, 256, 0, stream>>>(bfA, bfB, W2T + 2*(size_t)HD*HD, W2T + 3*(size_t)HD*HD,
                                          bfC, b2, pS, pQ, NN);

  // GraphNorm 2 affine from GEMM-fused partials
  k_colsum<<<dim3(2, RCH), 256, 0, stream>>>(pS, pQ, GRIDM, (GRIDM + RCH - 1)/RCH, pS2, pQ2);
  k_redaff<<<2, 256, 0, stream>>>(pS2, pQ2, g2w, g2b, g2a, scb, shb);

  // Layer 3: fused-norm narrow linears, then Horner with width-4 propagations
  k_lin3<<<gridP, 256, 0, stream>>>(bfC, scb, shb, W3, p0, p1, p2, p3);
  k_prop4<<<gridN, TPB, 0, stream>>>(row_ptr, edges, p3, nullptr, nullptr, nullptr, t1);
  k_prop4<<<gridN, TPB, 0, stream>>>(row_ptr, edges, p2, t1, nullptr, nullptr, t2);
  k_prop4<<<gridN, TPB, 0, stream>>>(row_ptr, edges, p1, t2, p0, b3, (f4*)d_out);
}

// Round 17
// 862.383 us; speedup vs baseline: 1.0115x; 1.0115x over previous
//
#include <hip/hip_runtime.h>
#include <math.h>

// Problem constants
#define NN 50000      // nodes
#define NE 800000     // edges
#define HD 512        // hidden
#define GN_EPS 1e-5f
#define NBCHUNK 196   // ceil(NN/256) for scan
#define GRIDM 391     // ceil(NN/128) GEMM row panels (BM=128)
#define STATS_NB 512  // combine1 stats partial blocks
#define RCH 64        // reduction chunks

typedef __attribute__((ext_vector_type(4))) float f4;
typedef __attribute__((ext_vector_type(4))) float f32x4;
typedef __attribute__((ext_vector_type(8))) short short8;
typedef unsigned short u16;
typedef __attribute__((ext_vector_type(4))) unsigned short us4;
typedef __attribute__((ext_vector_type(8))) unsigned short us8;

typedef struct { int s; float w; } edge_t;   // packed (src, norm) 8B

static __device__ __forceinline__ float elu1(float v){ return v > 0.f ? v : expm1f(v); }

static __device__ __forceinline__ float bf2f(u16 u){
  union { unsigned int i; float f; } v; v.i = ((unsigned int)u) << 16; return v.f;
}
static __device__ __forceinline__ u16 f2bf(float f){
  union { float f; unsigned int i; } v; v.f = f;
  unsigned int b = v.i;
  b += 0x7FFFu + ((b >> 16) & 1u);   // round-to-nearest-even
  return (u16)(b >> 16);
}

// A/B tile LDS address ([row][128B]): XOR 16B-slot index with (row&7); both-side swizzle.
static __device__ __forceinline__ int lds_addr(int row, int chunkByte){
  return row*128 + (chunkByte ^ ((row & 7) << 4));
}
// C tile LDS address in u16 units ([row][128 u16]): XOR 8-u16 chunk index with (row&7).
static __device__ __forceinline__ int ct_addr(int row, int col){
  return row*128 + (col ^ ((row & 7) << 3));
}

// ---------------- CSR build ----------------
__global__ void k_deg(const int* __restrict__ dst, const float* __restrict__ w,
                      float* __restrict__ deg, int* __restrict__ cnt) {
  int e = blockIdx.x*256 + threadIdx.x;
  if (e < NE) {
    int d = dst[e];
    atomicAdd(&deg[d], w[e]);
    atomicAdd(&cnt[d], 1);
  }
}

// hierarchical scan: chunk-local inclusive -> chunk totals; also deg -> rsqrt in place
__global__ void __launch_bounds__(256) k_scanA(const int* __restrict__ cnt,
                                               int* __restrict__ row_ptr,
                                               int* __restrict__ btot,
                                               float* __restrict__ deg) {
  __shared__ int sh[256];
  int t = threadIdx.x, b = blockIdx.x;
  int i = b*256 + t;
  if (i < NN) { float d = deg[i]; deg[i] = d > 0.f ? rsqrtf(d) : 0.f; }
  int v = (i < NN) ? cnt[i] : 0;
  sh[t] = v; __syncthreads();
  #pragma unroll
  for (int off = 1; off < 256; off <<= 1) {
    int x = (t >= off) ? sh[t-off] : 0;
    __syncthreads();
    sh[t] += x;
    __syncthreads();
  }
  if (i < NN) row_ptr[i+1] = sh[t];
  if (t == 255) btot[b] = sh[255];
}

__global__ void __launch_bounds__(256) k_scanB(const int* __restrict__ btot,
                                               int* __restrict__ boff) {
  __shared__ int sh[256];
  int t = threadIdx.x;
  int v = (t < NBCHUNK) ? btot[t] : 0;
  sh[t] = v; __syncthreads();
  #pragma unroll
  for (int off = 1; off < 256; off <<= 1) {
    int x = (t >= off) ? sh[t-off] : 0;
    __syncthreads();
    sh[t] += x;
    __syncthreads();
  }
  if (t < NBCHUNK) boff[t] = sh[t] - v;   // exclusive
}

__global__ void __launch_bounds__(256) k_scanC(int* __restrict__ row_ptr,
                                               const int* __restrict__ boff) {
  int t = threadIdx.x, b = blockIdx.x;
  int i = b*256 + t;
  if (i < NN) row_ptr[i+1] += boff[b];
  if (i == 0) row_ptr[0] = 0;
}

__global__ void k_fill(const int* __restrict__ src, const int* __restrict__ dst,
                       const float* __restrict__ w, const float* __restrict__ dinv,
                       const int* __restrict__ row_ptr, int* __restrict__ cursor,
                       edge_t* __restrict__ edges) {
  int e = blockIdx.x*256 + threadIdx.x;
  if (e < NE) {
    int s = src[e], d = dst[e];
    int pos = atomicAdd(&cursor[d], 1);
    int idx = row_ptr[d] + pos;
    edge_t ed; ed.s = s; ed.w = dinv[s] * w[e] * dinv[d];
    edges[idx] = ed;
  }
}

// ---------------- width-4 propagation (layers 1 & 3), 4-edge pipelined ----------------
__global__ void k_prop4(const int* __restrict__ row_ptr, const edge_t* __restrict__ edges,
                        const f4* __restrict__ in1, const f4* __restrict__ in2,
                        const f4* __restrict__ base, const float* __restrict__ bias,
                        f4* __restrict__ out) {
  int n = blockIdx.x*256 + threadIdx.x;
  if (n >= NN) return;
  f4 acc = {0.f,0.f,0.f,0.f};
  int e0 = row_ptr[n], e1 = row_ptr[n+1];
  int e = e0;
  if (in2) {
    for (; e + 4 <= e1; e += 4) {
      edge_t d0 = edges[e], d1 = edges[e+1], d2 = edges[e+2], d3 = edges[e+3];
      f4 a0 = in1[d0.s] + in2[d0.s];
      f4 a1 = in1[d1.s] + in2[d1.s];
      f4 a2 = in1[d2.s] + in2[d2.s];
      f4 a3 = in1[d3.s] + in2[d3.s];
      acc += d0.w*a0 + d1.w*a1 + d2.w*a2 + d3.w*a3;
    }
    for (; e < e1; ++e) {
      edge_t ed = edges[e];
      acc += ed.w * (in1[ed.s] + in2[ed.s]);
    }
  } else {
    for (; e + 4 <= e1; e += 4) {
      edge_t d0 = edges[e], d1 = edges[e+1], d2 = edges[e+2], d3 = edges[e+3];
      f4 a0 = in1[d0.s], a1 = in1[d1.s], a2 = in1[d2.s], a3 = in1[d3.s];
      acc += d0.w*a0 + d1.w*a1 + d2.w*a2 + d3.w*a3;
    }
    for (; e < e1; ++e) {
      edge_t ed = edges[e];
      acc += ed.w * in1[ed.s];
    }
  }
  if (base) acc += base[n];
  if (bias) { acc[0]+=bias[0]; acc[1]+=bias[1]; acc[2]+=bias[2]; acc[3]+=bias[3]; }
  out[n] = acc;
}

// ---------------- width-512 propagation on bf16 (row-major), 8-edge pipelined ----------------
// NRM=1: out = sc * (sum w v) + sh * (sum w)  (GraphNorm affine folded into the gather)
template<int NRM>
__global__ void __launch_bounds__(256) k_prop512_bf(
    const int* __restrict__ row_ptr, const edge_t* __restrict__ edges,
    const u16* __restrict__ in, u16* __restrict__ out,
    const float* __restrict__ sc, const float* __restrict__ sh) {
  int wv = threadIdx.x >> 6;
  int l  = threadIdx.x & 63;
  int n = blockIdx.x*4 + wv;
  if (n >= NN) return;
  int e0 = row_ptr[n], e1 = row_ptr[n+1];
  float acc[8] = {0.f,0.f,0.f,0.f,0.f,0.f,0.f,0.f};
  float wsum = 0.f;
  const u16* basep = in + l*8;
  int e = e0;
  for (; e + 8 <= e1; e += 8) {
    edge_t ed[8];
    us8 v[8];
    #pragma unroll
    for (int j = 0; j < 8; ++j) ed[j] = edges[e+j];
    #pragma unroll
    for (int j = 0; j < 8; ++j)
      v[j] = *reinterpret_cast<const us8*>(basep + (size_t)ed[j].s*HD);
    #pragma unroll
    for (int q = 0; q < 8; ++q) {
      float s = 0.f;
      #pragma unroll
      for (int j = 0; j < 8; ++j) s += ed[j].w * bf2f(v[j][q]);
      acc[q] += s;
    }
    if (NRM) {
      #pragma unroll
      for (int j = 0; j < 8; ++j) wsum += ed[j].w;
    }
  }
  for (; e < e1; ++e) {
    edge_t ed = edges[e];
    us8 v = *reinterpret_cast<const us8*>(basep + (size_t)ed.s*HD);
    #pragma unroll
    for (int q = 0; q < 8; ++q) acc[q] += ed.w * bf2f(v[q]);
    if (NRM) wsum += ed.w;
  }
  us8 o;
  if (NRM) {
    #pragma unroll
    for (int q = 0; q < 8; ++q)
      o[q] = f2bf(sc[l*8+q]*acc[q] + sh[l*8+q]*wsum);
  } else {
    #pragma unroll
    for (int q = 0; q < 8; ++q) o[q] = f2bf(acc[q]);
  }
  *reinterpret_cast<us8*>(out + (size_t)n*HD + l*8) = o;
}

// ---------------- layer-1 combine fused with stats: bf16 out + column partials ----------------
__global__ void __launch_bounds__(256) k_combine1s(
    const f4* __restrict__ x, const f4* __restrict__ h1, const f4* __restrict__ h2,
    const f4* __restrict__ h3, const float* __restrict__ W1, const float* __restrict__ b1,
    u16* __restrict__ act, float* __restrict__ pS, float* __restrict__ pQ) {
  __shared__ float sdS[HD], sdQ[HD];
  int t = threadIdx.x;
  int half = t >> 7;
  int c4 = (t & 127) * 4;
  f4 wcol[16];
  #pragma unroll
  for (int kf = 0; kf < 16; ++kf)
    wcol[kf] = *reinterpret_cast<const f4*>(W1 + (size_t)kf*HD + c4);
  f4 bv = *reinterpret_cast<const f4*>(b1 + c4);
  f4 s = {0.f,0.f,0.f,0.f}, qq = {0.f,0.f,0.f,0.f};
  for (int n = blockIdx.x*2 + half; n < NN; n += gridDim.x*2) {
    f4 hv0 = x[n], hv1 = h1[n], hv2 = h2[n], hv3 = h3[n];
    f4 acc = bv;
    #pragma unroll
    for (int f = 0; f < 4; ++f) acc += hv0[f] * wcol[f];
    #pragma unroll
    for (int f = 0; f < 4; ++f) acc += hv1[f] * wcol[4+f];
    #pragma unroll
    for (int f = 0; f < 4; ++f) acc += hv2[f] * wcol[8+f];
    #pragma unroll
    for (int f = 0; f < 4; ++f) acc += hv3[f] * wcol[12+f];
    us4 o;
    #pragma unroll
    for (int e = 0; e < 4; ++e) {
      float v = elu1(acc[e]);
      s[e] += v; qq[e] += v*v;
      o[e] = f2bf(v);
    }
    *reinterpret_cast<us4*>(act + (size_t)n*HD + c4) = o;
  }
  if (half) {
    *reinterpret_cast<f4*>(&sdS[c4]) = s;
    *reinterpret_cast<f4*>(&sdQ[c4]) = qq;
  }
  __syncthreads();
  if (!half) {
    f4 ts = *reinterpret_cast<f4*>(&sdS[c4]) + s;
    f4 tq = *reinterpret_cast<f4*>(&sdQ[c4]) + qq;
    *reinterpret_cast<f4*>(&pS[(size_t)blockIdx.x*HD + c4]) = ts;
    *reinterpret_cast<f4*>(&pQ[(size_t)blockIdx.x*HD + c4]) = tq;
  }
}

// ---------------- stage-1 column reduce: [nb][512] -> [RCH][512] ----------------
__global__ void __launch_bounds__(256) k_colsum(
    const float* __restrict__ pS, const float* __restrict__ pQ, int nb, int chunk,
    float* __restrict__ pS2, float* __restrict__ pQ2) {
  int c = blockIdx.x*256 + threadIdx.x;   // 0..511 over grid.x==2
  int y = blockIdx.y;                     // 0..RCH-1
  int i0 = y*chunk;
  int i1 = i0 + chunk; if (i1 > nb) i1 = nb;
  float a = 0.f, b = 0.f;
  for (int i = i0; i < i1; ++i) {
    a += pS[(size_t)i*HD + c];
    b += pQ[(size_t)i*HD + c];
  }
  pS2[(size_t)y*HD + c] = a;
  pQ2[(size_t)y*HD + c] = b;
}

// ---------------- stage-2: reduce RCH partials + GraphNorm affine ----------------
__global__ void __launch_bounds__(256) k_redaff(
    const float* __restrict__ pS2, const float* __restrict__ pQ2,
    const float* __restrict__ gw, const float* __restrict__ gb,
    const float* __restrict__ ga,
    float* __restrict__ sc, float* __restrict__ sh) {
  int c = blockIdx.x*256 + threadIdx.x;
  if (c >= HD) return;
  float a = 0.f, b = 0.f;
  #pragma unroll 8
  for (int i = 0; i < RCH; ++i) {
    a += pS2[(size_t)i*HD + c];
    b += pQ2[(size_t)i*HD + c];
  }
  float mu = a*(1.f/NN);
  float al = ga[c];
  float var = b*(1.f/NN) - 2.f*al*mu*mu + al*al*mu*mu;
  float inv = rsqrtf(var + GN_EPS);
  sc[c] = gw[c]*inv;
  sh[c] = gb[c] - gw[c]*inv*al*mu;
}

// ---------------- W2 -> bf16 transposed: Bt[k][out][in] = bf16(W2[k][in][out]) ----------------
__global__ void k_w2t(const float* __restrict__ W2, u16* __restrict__ Bt) {
  size_t idx = (size_t)blockIdx.x*256 + threadIdx.x;
  if (idx >= (size_t)4*HD*HD) return;
  int i = (int)(idx & 511);          // in  (fastest -> coalesced write)
  int o = (int)((idx >> 9) & 511);   // out
  int k = (int)(idx >> 18);
  Bt[idx] = f2bf(W2[((size_t)k*HD + i)*HD + o]);
}

// W0 slice with sc folded: Bt0[o][i] = bf16(sc[i]*W2[0][i][o])
__global__ void k_w2t0(const float* __restrict__ W2, const float* __restrict__ sc,
                       u16* __restrict__ Bt0) {
  size_t idx = (size_t)blockIdx.x*256 + threadIdx.x;
  if (idx >= (size_t)HD*HD) return;
  int i = (int)(idx & 511);
  int o = (int)(idx >> 9);
  Bt0[idx] = f2bf(sc[i] * W2[(size_t)i*HD + o]);
}

// cvec stage 1: cpart[y][o] = sum_{i in chunk y} sh[i]*W2[0][i][o]  (8 rows/chunk)
__global__ void __launch_bounds__(256) k_cvecp(const float* __restrict__ W2,
                                               const float* __restrict__ sh,
                                               float* __restrict__ cpart) {
  int o = blockIdx.x*256 + threadIdx.x;   // grid.x==2
  int y = blockIdx.y;                     // 0..63
  float a = 0.f;
  #pragma unroll
  for (int i = y*8; i < y*8 + 8; ++i) a += sh[i]*W2[(size_t)i*HD + o];
  cpart[(size_t)y*HD + o] = a;
}

// cvec stage 2
__global__ void __launch_bounds__(256) k_cvecr(const float* __restrict__ cpart,
                                               float* __restrict__ cvec) {
  int o = blockIdx.x*256 + threadIdx.x;
  if (o >= HD) return;
  float a = 0.f;
  #pragma unroll 8
  for (int y = 0; y < 64; ++y) a += cpart[(size_t)y*HD + o];
  cvec[o] = a;
}

// ---------------- MFMA bf16 dual-source GEMM (K=1024): Cbf (+)= A0@B0^T + A1@B1^T ----------------
// 2-deep A prefetch, 1-deep B. LDS exactly 32KB (5 blocks/CU): FINAL stats go to GLOBAL
// pS/pQ via atomicAdd (exactly 2 f32 contribs/slot -> order-invariant, deterministic).
#define BM 128
#define BN 128
#define BKS 64
template<int FINAL>
__global__ void __launch_bounds__(256) k_gemm2(
    const u16* __restrict__ A0, const u16* __restrict__ A1,
    const u16* __restrict__ B0, const u16* __restrict__ B1,
    u16* __restrict__ Cbf, const float* __restrict__ bias,
    float* __restrict__ pS, float* __restrict__ pQ, int M) {
  __shared__ u16 smem[BM*BKS*2];   // exactly 32 KB: As|Bs in K-loop, C tile in epilogue
  u16* As = smem;
  u16* Bs = smem + BM*BKS;
  int t = threadIdx.x;

  // XCD-bijective remap (m204), col-fastest within consecutive ids
  int nwg = gridDim.x;            // GRIDM*4
  int q = nwg >> 3, r = nwg & 7;
  int xcd = blockIdx.x & 7, sub = blockIdx.x >> 3;
  int nid = (xcd < r ? xcd*(q+1) : r*(q+1) + (xcd - r)*q) + sub;
  int bmi = nid >> 2;             // row-panel index (0..GRIDM-1)
  int bni = nid & 3;              // col-panel index (0..3)
  int bm = bmi * BM, bn = bni * BN;

  int w  = t >> 6;
  int l  = t & 63;
  int wr = (w >> 1) * 64;
  int wc = (w & 1) * 64;
  int lr = l & 15;
  int lq = l >> 4;

  // staging map: 4 slots/thread; slot s -> row = s>>3, 16B-chunk c8 = s&7
  size_t aoffs[4], boffs[4];
  int wb[4];
  #pragma unroll
  for (int p2 = 0; p2 < 4; ++p2) {
    int s = p2*256 + t;
    int row = s >> 3, c8 = s & 7;
    int ga = bm + row; if (ga >= M) ga = M - 1;
    aoffs[p2] = (size_t)ga*HD + c8*8;
    boffs[p2] = (size_t)(bn + row)*HD + c8*8;
    wb[p2] = lds_addr(row, c8*16);
  }

  f32x4 acc[4][4];
  #pragma unroll
  for (int i = 0; i < 4; ++i)
    #pragma unroll
    for (int j = 0; j < 4; ++j) acc[i][j] = (f32x4){0.f,0.f,0.f,0.f};

  us8 raP[4], raQ[4], rb[4];
  #pragma unroll
  for (int p2 = 0; p2 < 4; ++p2) {
    raP[p2] = *reinterpret_cast<const us8*>(A0 + aoffs[p2]);          // A k-tile 0
    raQ[p2] = *reinterpret_cast<const us8*>(A0 + aoffs[p2] + BKS);    // A k-tile 1
    rb[p2]  = *reinterpret_cast<const us8*>(B0 + boffs[p2]);          // B k-tile 0
  }

#define GEMM_ITER(RA, H)                                                      \
  {                                                                           \
    __syncthreads();                                                          \
    _Pragma("unroll")                                                         \
    for (int p2 = 0; p2 < 4; ++p2) {                                          \
      *reinterpret_cast<us8*>((char*)As + wb[p2]) = RA[p2];                   \
      *reinterpret_cast<us8*>((char*)Bs + wb[p2]) = rb[p2];                   \
    }                                                                         \
    if ((H) + 1 < 16) {                                                       \
      const u16* Bsrc = ((H)+1 < 8) ? B0 : B1;                                \
      int offB = (((H)+1) & 7) * BKS;                                         \
      _Pragma("unroll")                                                       \
      for (int p2 = 0; p2 < 4; ++p2)                                          \
        rb[p2] = *reinterpret_cast<const us8*>(Bsrc + boffs[p2] + offB);      \
    }                                                                         \
    if ((H) + 2 < 16) {                                                       \
      const u16* Asrc = ((H)+2 < 8) ? A0 : A1;                                \
      int offA = (((H)+2) & 7) * BKS;                                         \
      _Pragma("unroll")                                                       \
      for (int p2 = 0; p2 < 4; ++p2)                                          \
        RA[p2] = *reinterpret_cast<const us8*>(Asrc + aoffs[p2] + offA);      \
    }                                                                         \
    __syncthreads();                                                          \
    _Pragma("unroll")                                                         \
    for (int ks = 0; ks < 2; ++ks) {                                          \
      short8 af[4], bfr[4];                                                   \
      _Pragma("unroll")                                                       \
      for (int mi = 0; mi < 4; ++mi)                                          \
        af[mi] = *reinterpret_cast<const short8*>(                            \
            (char*)As + lds_addr(wr + mi*16 + lr, ks*64 + lq*16));            \
      _Pragma("unroll")                                                       \
      for (int ni = 0; ni < 4; ++ni)                                          \
        bfr[ni] = *reinterpret_cast<const short8*>(                           \
            (char*)Bs + lds_addr(wc + ni*16 + lr, ks*64 + lq*16));            \
      _Pragma("unroll")                                                       \
      for (int mi = 0; mi < 4; ++mi)                                          \
        _Pragma("unroll")                                                     \
        for (int ni = 0; ni < 4; ++ni)                                        \
          acc[mi][ni] = __builtin_amdgcn_mfma_f32_16x16x32_bf16(              \
              af[mi], bfr[ni], acc[mi][ni], 0, 0, 0);                         \
    }                                                                         \
  }

  #pragma unroll
  for (int j = 0; j < 8; ++j) {
    GEMM_ITER(raP, 2*j)
    GEMM_ITER(raQ, 2*j + 1)
  }
#undef GEMM_ITER

  // -------- epilogue: LDS-staged coalesced C path; stats straight to global --------
  __syncthreads();   // all ds_reads of the last tile done; smem now reusable as C tile

  int crow = t >> 1, chh = t & 1;              // cooperative row / half assignment
  if (FINAL) {
    if (bm + crow < M) {                       // coalesced load of old C into LDS
      #pragma unroll
      for (int c = 0; c < 8; ++c) {
        int col = chh*64 + c*8;
        us8 v = *reinterpret_cast<const us8*>(&Cbf[(size_t)(bm+crow)*HD + bn + col]);
        *reinterpret_cast<us8*>(&smem[ct_addr(crow, col)]) = v;
      }
    }
    __syncthreads();
  }

  float psum[4] = {0.f,0.f,0.f,0.f}, qsum[4] = {0.f,0.f,0.f,0.f};
  #pragma unroll
  for (int ni = 0; ni < 4; ++ni) {
    int coln = wc + ni*16 + lr;
    float bgn = bias ? bias[bn + coln] : 0.f;
    #pragma unroll
    for (int mi = 0; mi < 4; ++mi)
      #pragma unroll
      for (int rr = 0; rr < 4; ++rr) {
        int row = wr + mi*16 + lq*4 + rr;
        int ca = ct_addr(row, coln);
        if (!FINAL) {
          smem[ca] = f2bf(acc[mi][ni][rr] + bgn);
        } else if (bm + row < M) {
          float v = elu1(bf2f(smem[ca]) + acc[mi][ni][rr] + bgn);
          smem[ca] = f2bf(v);
          psum[ni] += v; qsum[ni] += v*v;
        }
      }
  }
  if (FINAL) {
    #pragma unroll
    for (int ni = 0; ni < 4; ++ni) {
      psum[ni] += __shfl_xor(psum[ni], 16, 64);
      psum[ni] += __shfl_xor(psum[ni], 32, 64);
      qsum[ni] += __shfl_xor(qsum[ni], 16, 64);
      qsum[ni] += __shfl_xor(qsum[ni], 32, 64);
    }
    if (lq == 0) {
      #pragma unroll
      for (int ni = 0; ni < 4; ++ni) {
        int coln = wc + ni*16 + lr;
        atomicAdd(&pS[(size_t)bmi*HD + bn + coln], psum[ni]);  // 2 contribs/slot
        atomicAdd(&pQ[(size_t)bmi*HD + bn + coln], qsum[ni]);
      }
    }
  }
  __syncthreads();   // C tile complete

  if (bm + crow < M) {                          // coalesced store of C tile
    #pragma unroll
    for (int c = 0; c < 8; ++c) {
      int col = chh*64 + c*8;
      us8 v = *reinterpret_cast<const us8*>(&smem[ct_addr(crow, col)]);
      *reinterpret_cast<us8*>(&Cbf[(size_t)(bm+crow)*HD + bn + col]) = v;
    }
  }
}

// ---------------- layer-3 linears (bf16 act) with fused GraphNorm affine ----------------
__global__ void __launch_bounds__(256) k_lin3(
    const u16* __restrict__ act, const float* __restrict__ sc, const float* __restrict__ sh,
    const float* __restrict__ W3,
    f4* __restrict__ p0, f4* __restrict__ p1, f4* __restrict__ p2, f4* __restrict__ p3) {
  int wave = threadIdx.x / 64;
  int lane = threadIdx.x % 64;
  int n = blockIdx.x*4 + wave;
  if (n >= NN) return;
  float part[4][4] = {};
  #pragma unroll
  for (int jj = 0; jj < 8; ++jj) {
    int j = lane + jj*64;
    float v = sc[j]*bf2f(act[(size_t)n*HD + j]) + sh[j];
    #pragma unroll
    for (int k = 0; k < 4; ++k) {
      f4 wv = *reinterpret_cast<const f4*>(W3 + ((size_t)k*HD + j)*4);
      #pragma unroll
      for (int c = 0; c < 4; ++c) part[k][c] += v * wv[c];
    }
  }
  #pragma unroll
  for (int k = 0; k < 4; ++k)
    #pragma unroll
    for (int c = 0; c < 4; ++c) {
      float s = part[k][c];
      #pragma unroll
      for (int off = 32; off >= 1; off >>= 1) s += __shfl_xor(s, off, 64);
      part[k][c] = s;
    }
  if (lane == 0) {
    f4 v0 = {part[0][0],part[0][1],part[0][2],part[0][3]};
    f4 v1 = {part[1][0],part[1][1],part[1][2],part[1][3]};
    f4 v2 = {part[2][0],part[2][1],part[2][2],part[2][3]};
    f4 v3 = {part[3][0],part[3][1],part[3][2],part[3][3]};
    p0[n]=v0; p1[n]=v1; p2[n]=v2; p3[n]=v3;
  }
}

// ---------------- host launch ----------------
extern "C" void kernel_launch(void* const* d_in, const int* in_sizes, int n_in,
                              void* d_out, int out_size, void* d_ws, size_t ws_size,
                              hipStream_t stream) {
  const float* x   = (const float*)d_in[0];
  const int*   ei  = (const int*)d_in[1];
  const int*   src = ei;
  const int*   dst = ei + NE;
  const float* w   = (const float*)d_in[2];
  const float* W1  = (const float*)d_in[3];
  const float* b1  = (const float*)d_in[4];
  const float* W2  = (const float*)d_in[5];
  const float* b2  = (const float*)d_in[6];
  const float* W3  = (const float*)d_in[7];
  const float* b3  = (const float*)d_in[8];
  const float* g1w = (const float*)d_in[9];
  const float* g1b = (const float*)d_in[10];
  const float* g1a = (const float*)d_in[11];
  const float* g2w = (const float*)d_in[12];
  const float* g2b = (const float*)d_in[13];
  const float* g2a = (const float*)d_in[14];

  char* p = (char*)d_ws;
  auto alloc = [&](size_t bytes) -> void* {
    void* r = (void*)p;
    p += (bytes + 255) & ~(size_t)255;
    return r;
  };
  float* deg      = (float*)alloc(NN*4);
  int*   cnt      = (int*)  alloc(NN*4);
  int*   row_ptr  = (int*)  alloc((NN+1)*4);
  int*   cursor   = (int*)  alloc(NN*4);
  int*   btot     = (int*)  alloc(256*4);
  int*   boff     = (int*)  alloc(256*4);
  edge_t* edges   = (edge_t*)alloc((size_t)NE*8);
  f4*    h1       = (f4*)   alloc((size_t)NN*16);
  f4*    h2       = (f4*)   alloc((size_t)NN*16);
  f4*    h3       = (f4*)   alloc((size_t)NN*16);
  f4*    p0       = (f4*)   alloc((size_t)NN*16);
  f4*    p1       = (f4*)   alloc((size_t)NN*16);
  f4*    p2       = (f4*)   alloc((size_t)NN*16);
  f4*    p3       = (f4*)   alloc((size_t)NN*16);
  f4*    t1       = (f4*)   alloc((size_t)NN*16);
  f4*    t2       = (f4*)   alloc((size_t)NN*16);
  float* scb      = (float*)alloc(HD*4);
  float* shb      = (float*)alloc(HD*4);
  float* cvec     = (float*)alloc(HD*4);
  float* pS       = (float*)alloc((size_t)STATS_NB*HD*4);   // 1 MB
  float* pQ       = (float*)alloc((size_t)STATS_NB*HD*4);   // 1 MB
  float* pS2      = (float*)alloc((size_t)RCH*HD*4);        // 128 KB
  float* pQ2      = (float*)alloc((size_t)RCH*HD*4);        // 128 KB
  float* cpart    = (float*)alloc((size_t)RCH*HD*4);        // 128 KB
  u16*   W2T      = (u16*)  alloc((size_t)4*HD*HD*2);       // 2 MB
  // big buffers: 3 x 51.2 MB bf16  (~175 MB total)
  u16*   bfA      = (u16*)  alloc((size_t)NN*HD*2);
  u16*   bfB      = (u16*)  alloc((size_t)NN*HD*2);
  u16*   bfC      = (u16*)  alloc((size_t)NN*HD*2);   // C partial then act2

  const int TPB = 256;
  int gridE = (NE + TPB - 1)/TPB;
  int gridN = (NN + TPB - 1)/TPB;
  int gridP = (NN + 3)/4;

  // CSR + norm
  hipMemsetAsync(deg, 0, NN*4, stream);
  hipMemsetAsync(cnt, 0, NN*4, stream);
  k_deg<<<gridE, TPB, 0, stream>>>(dst, w, deg, cnt);
  k_scanA<<<NBCHUNK, 256, 0, stream>>>(cnt, row_ptr, btot, deg);
  k_scanB<<<1, 256, 0, stream>>>(btot, boff);
  k_scanC<<<NBCHUNK, 256, 0, stream>>>(row_ptr, boff);
  hipMemsetAsync(cursor, 0, NN*4, stream);
  k_fill<<<gridE, TPB, 0, stream>>>(src, dst, w, deg, row_ptr, cursor, edges);
  k_w2t<<<(4*HD*HD + 255)/256, 256, 0, stream>>>(W2, W2T);

  // Layer 1: hops, then fused combine+ELU+stats -> bf16 act (pre-norm) in bfA
  k_prop4<<<gridN, TPB, 0, stream>>>(row_ptr, edges, (const f4*)x, nullptr, nullptr, nullptr, h1);
  k_prop4<<<gridN, TPB, 0, stream>>>(row_ptr, edges, h1, nullptr, nullptr, nullptr, h2);
  k_prop4<<<gridN, TPB, 0, stream>>>(row_ptr, edges, h2, nullptr, nullptr, nullptr, h3);
  k_combine1s<<<STATS_NB, 256, 0, stream>>>((const f4*)x, h1, h2, h3, W1, b1, bfA, pS, pQ);
  k_colsum<<<dim3(2, RCH), 256, 0, stream>>>(pS, pQ, STATS_NB, (STATS_NB + RCH - 1)/RCH, pS2, pQ2);
  k_redaff<<<2, 256, 0, stream>>>(pS2, pQ2, g1w, g1b, g1a, scb, shb);

  // Fold GraphNorm-1 into the GEMM path: W0' = diag(sc)W0, cvec = sh^T W0
  k_w2t0<<<(HD*HD + 255)/256, 256, 0, stream>>>(W2, scb, W2T);
  k_cvecp<<<dim3(2, 64), 256, 0, stream>>>(W2, shb, cpart);
  k_cvecr<<<2, 256, 0, stream>>>(cpart, cvec);

  // Zero stats accumulators for GEMM2's global-atomic stats (pS/pQ free after colsum above)
  hipMemsetAsync(pS, 0, (size_t)GRIDM*HD*4, stream);
  hipMemsetAsync(pQ, 0, (size_t)GRIDM*HD*4, stream);

  // Layer 2: h0=bfA (pre-norm), h1 = NRM-prop(h0) = bfB (normalized inline);
  //          GEMM1 (W0'+cvec, W1) writes Cbf; h2=prop(h1)=bfA, h3=prop(h2)=bfB;
  //          GEMM2 (W2,W3) RMW + bias+ELU+stats (global atomics)
  k_prop512_bf<1><<<gridP, 256, 0, stream>>>(row_ptr, edges, bfA, bfB, scb, shb);
  k_gemm2<0><<<GRIDM*4, 256, 0, stream>>>(bfA, bfB, W2T, W2T + (size_t)HD*HD,
                                          bfC, cvec, nullptr, nullptr, NN);
  k_prop512_bf<0><<<gridP, 256, 0, stream>>>(row_ptr, edges, bfB, bfA, nullptr, nullptr);
  k_prop512_bf<0><<<gridP, 256, 0, stream>>>(row_ptr, edges, bfA, bfB, nullptr, nullptr);
  k_gemm2<1><<<GRIDM*4, 256, 0, stream>>>(bfA, bfB, W2T + 2*(size_t)HD*HD, W2T + 3*(size_t)HD*HD,
                                          bfC, b2, pS, pQ, NN);

  // GraphNorm 2 affine from GEMM-fused partials
  k_colsum<<<dim3(2, RCH), 256, 0, stream>>>(pS, pQ, GRIDM, (GRIDM + RCH - 1)/RCH, pS2, pQ2);
  k_redaff<<<2, 256, 0, stream>>>(pS2, pQ2, g2w, g2b, g2a, scb, shb);

  // Layer 3: fused-norm narrow linears, then Horner with width-4 propagations
  k_lin3<<<gridP, 256, 0, stream>>>(bfC, scb, shb, W3, p0, p1, p2, p3);
  k_prop4<<<gridN, TPB, 0, stream>>>(row_ptr, edges, p3, nullptr, nullptr, nullptr, t1);
  k_prop4<<<gridN, TPB, 0, stream>>>(row_ptr, edges, p2, t1, nullptr, nullptr, t2);
  k_prop4<<<gridN, TPB, 0, stream>>>(row_ptr, edges, p1, t2, p0, b3, (f4*)d_out);
}